// Round 12
// baseline (194.084 us; speedup 1.0000x reference)
//
#include <hip/hip_runtime.h>
#include <math.h>

#define H    768
#define NT   12           // H/64 K-tiles
#define DIM  128
#define LQ   32
#define LD   512
#define BM   128          // tokens per block
#define EPSF 1e-12f

typedef _Float16 f16x8 __attribute__((ext_vector_type(8)));
typedef _Float16 f16x4 __attribute__((ext_vector_type(4)));
typedef float    f32x4 __attribute__((ext_vector_type(4)));

static __device__ __forceinline__ unsigned short h2u(_Float16 h) {
    return __builtin_bit_cast(unsigned short, h);
}

#define GLOAD_LDS16(g, l) __builtin_amdgcn_global_load_lds(                    \
    (const __attribute__((address_space(1))) unsigned int*)(const void*)(g),   \
    (__attribute__((address_space(3))) unsigned int*)(void*)(l), 16, 0, 0)

// ------- W -> single f16 [ks][dim][64 swizzled] (16 KB/tile) + WT fp32 -------
__global__ __launch_bounds__(256) void wconv_kernel(
    const float* __restrict__ W, unsigned short* __restrict__ wsW,
    float* __restrict__ WT)
{
    const int ks  = blockIdx.x;          // 0..11, K-tile of 64
    const int tid = threadIdx.x;
    #pragma unroll 8
    for (int i = 0; i < 32; ++i) {
        const int idx = tid + i * 256;          // 0..8191
        const int row = idx >> 6, col = idx & 63;
        const float x = W[(size_t)row * H + ks * 64 + col];
        const int colS = (((col >> 3) ^ (row & 7)) << 3) | (col & 7);
        wsW[((size_t)ks * 128 + row) * 64 + colS] = h2u((_Float16)x);
        WT[((size_t)ks * 64 + col) * DIM + row] = x;
    }
}

// ------- query projection (coalesced via WT, 2-way h-split) + L2 norm -------
__global__ __launch_bounds__(256) void qproj_kernel(
    const float* __restrict__ qh, const float* __restrict__ WT,
    unsigned short* __restrict__ qn)
{
    const int blk = blockIdx.x;   // 4 tokens per block
    const int tid = threadIdx.x;
    const int td  = tid & 127;    // output dim
    const int hp  = tid >> 7;     // h-half
    __shared__ float rows[4][H];
    __shared__ float psum[2][4][128];
    __shared__ float red[128];

    const float4* src = (const float4*)(qh + (size_t)blk * 4 * H);
    float4*       dst = (float4*)&rows[0][0];
    for (int i = tid; i < 4 * H / 4; i += 256) dst[i] = src[i];
    __syncthreads();

    float acc[4] = {0.f, 0.f, 0.f, 0.f};
    const int h0 = hp * (H / 2);
    #pragma unroll 8
    for (int h = h0; h < h0 + H / 2; ++h) {
        const float wv = WT[(size_t)h * DIM + td];
        acc[0] += wv * rows[0][h];
        acc[1] += wv * rows[1][h];
        acc[2] += wv * rows[2][h];
        acc[3] += wv * rows[3][h];
    }
    #pragma unroll
    for (int j = 0; j < 4; ++j) psum[hp][j][td] = acc[j];
    __syncthreads();

    #pragma unroll
    for (int j = 0; j < 4; ++j) {
        const float val = psum[0][j][td] + psum[1][j][td];
        if (hp == 0) red[td] = val * val;
        __syncthreads();
        for (int s = 64; s > 0; s >>= 1) {
            if (tid < s) red[tid] += red[tid + s];
            __syncthreads();
        }
        const float inv = 1.0f / fmaxf(sqrtf(red[0]), EPSF);
        if (hp == 0) qn[((size_t)blk * 4 + j) * DIM + td] = h2u((_Float16)(val * inv));
        __syncthreads();
    }
}

// -------- doc: BK=64 pipelined f16 MFMA, 8 waves, counted-vmcnt schedule -----
struct Smem {
    union {
        struct {  // GEMM stage: 32 KB A + 32 KB W
            unsigned short A[2][BM][64];
            unsigned short Wt[2][128][64];
        } g;
        unsigned short C[BM][DIM];   // epilogue: 32 KB (overlays GEMM region)
    } u;
    float         pnorm[4][BM];      // 2 KB
    unsigned char mk[BM];            // 128 B
    float         pmax[LQ][8];       // 1 KB
};

__global__ __launch_bounds__(512, 2) void docgemm_kernel(
    const float* __restrict__ dh, const unsigned short* __restrict__ wsW,
    const int* __restrict__ dmask, const unsigned short* __restrict__ qn,
    float* __restrict__ part, const int* __restrict__ ppq_p)
{
    __shared__ Smem sm;
    const int blk = blockIdx.x;      // 1024 blocks
    const int b   = blk >> 2;        // doc
    const int c   = blk & 3;         // 128-token chunk
    const int tid = threadIdx.x;
    const int w   = tid >> 6;        // wave 0..7
    const int wm  = w >> 2;          // token half (64 tokens)
    const int wn  = w & 3;           // dim quarter (32 dims)
    const int l   = tid & 63;
    const int g   = l >> 4;
    const int r15 = l & 15;
    const int ppq = ppq_p[0];

    // staging: thread -> rows r0 + i*32 (i=0..3), float4 segment seg0 (0..15)
    const int r0   = tid >> 4;       // 0..31
    const int seg0 = tid & 15;
    const int wgr  = seg0 >> 1;      // write granule
    const int wsub = (seg0 & 1) * 8; // byte sub-offset in granule

    const float* Abase = dh + ((size_t)b * LD + (size_t)c * BM) * H;

    f32x4 acc[4][2];
    #pragma unroll
    for (int m = 0; m < 4; ++m)
        #pragma unroll
        for (int n = 0; n < 2; ++n)
            acc[m][n] = (f32x4){0.f, 0.f, 0.f, 0.f};

    float4 avA[4];

    // ---- prologue: W(0) (oldest), A(0) -> convert, A(1) left in flight ----
    {
        const char* wt   = (const char*)wsW;
        char*       wdst = (char*)&sm.u.g.Wt[0][0][0];
        GLOAD_LDS16(wt + tid * 16,        wdst + w * 1024);
        GLOAD_LDS16(wt + 8192 + tid * 16, wdst + 8192 + w * 1024);
        __builtin_amdgcn_sched_barrier(0);
        #pragma unroll
        for (int i = 0; i < 4; ++i)
            avA[i] = *(const float4*)(Abase + (size_t)(r0 + i * 32) * H + seg0 * 4);
        #pragma unroll
        for (int i = 0; i < 4; ++i) {
            const int row = r0 + i * 32;
            f16x4 h;
            h[0] = (_Float16)avA[i].x; h[1] = (_Float16)avA[i].y;
            h[2] = (_Float16)avA[i].z; h[3] = (_Float16)avA[i].w;
            *(f16x4*)((char*)&sm.u.g.A[0][0][0] + row * 128 + (((wgr ^ (row & 7)) << 4) | wsub)) = h;
        }
        #pragma unroll
        for (int i = 0; i < 4; ++i)
            avA[i] = *(const float4*)(Abase + (size_t)(r0 + i * 32) * H + 64 + seg0 * 4);
        asm volatile("s_waitcnt vmcnt(4) lgkmcnt(0)" ::: "memory");
        __builtin_amdgcn_sched_barrier(0);
        __builtin_amdgcn_s_barrier();
        __builtin_amdgcn_sched_barrier(0);
    }

    // ---- main K-loop (12 steps): counted vmcnt keeps A(t+2) in flight ----
    for (int t = 0; t < NT; ++t) {
        const int cur = t & 1, nxt = cur ^ 1;

        if (t + 1 < NT) {  // W(t+1) — issued FIRST (oldest)
            const char* wt   = (const char*)wsW + (size_t)(t + 1) * 16384;
            char*       wdst = (char*)&sm.u.g.Wt[nxt][0][0];
            GLOAD_LDS16(wt + tid * 16,        wdst + w * 1024);
            GLOAD_LDS16(wt + 8192 + tid * 16, wdst + 8192 + w * 1024);
        }
        __builtin_amdgcn_sched_barrier(0);

        // fragment reads (A: 8 x b128, W: 4 x b128) + 16 MFMA
        const char* Ab = (const char*)&sm.u.g.A[cur][0][0];
        const char* Wb = (const char*)&sm.u.g.Wt[cur][0][0];
        f16x8 ah[2][4];
        #pragma unroll
        for (int ksub = 0; ksub < 2; ++ksub)
            #pragma unroll
            for (int m = 0; m < 4; ++m) {
                const int row = wm * 64 + m * 16 + r15;
                ah[ksub][m] = *(const f16x8*)(Ab + row * 128 + ((((ksub * 4 + g)) ^ (row & 7)) << 4));
            }
        __builtin_amdgcn_s_setprio(1);
        #pragma unroll
        for (int ksub = 0; ksub < 2; ++ksub) {
            #pragma unroll
            for (int n = 0; n < 2; ++n) {
                const int row = wn * 32 + n * 16 + r15;
                f16x8 bh = *(const f16x8*)(Wb + row * 128 + ((((ksub * 4 + g)) ^ (row & 7)) << 4));
                #pragma unroll
                for (int m = 0; m < 4; ++m)
                    acc[m][n] = __builtin_amdgcn_mfma_f32_16x16x32_f16(ah[ksub][m], bh, acc[m][n], 0, 0, 0);
            }
        }
        __builtin_amdgcn_s_setprio(0);

        if (t + 1 < NT) {  // convert avA (tile t+1 data) -> LDS buf[nxt]
            #pragma unroll
            for (int i = 0; i < 4; ++i) {
                const int row = r0 + i * 32;
                f16x4 h;
                h[0] = (_Float16)avA[i].x; h[1] = (_Float16)avA[i].y;
                h[2] = (_Float16)avA[i].z; h[3] = (_Float16)avA[i].w;
                *(f16x4*)((char*)&sm.u.g.A[nxt][0][0] + row * 128 + (((wgr ^ (row & 7)) << 4) | wsub)) = h;
            }
        }
        if (t + 2 < NT) {  // issue A(t+2) — youngest, stays in flight
            const int k0n = (t + 2) * 64;
            #pragma unroll
            for (int i = 0; i < 4; ++i)
                avA[i] = *(const float4*)(Abase + (size_t)(r0 + i * 32) * H + k0n + seg0 * 4);
        }

        if (t + 2 < NT) {
            asm volatile("s_waitcnt vmcnt(4) lgkmcnt(0)" ::: "memory");
        } else {
            asm volatile("s_waitcnt vmcnt(0) lgkmcnt(0)" ::: "memory");
        }
        __builtin_amdgcn_sched_barrier(0);
        __builtin_amdgcn_s_barrier();
        __builtin_amdgcn_sched_barrier(0);
    }

    // ---- epilogue 1: C -> LDS f16 (swizzled), norms from registers ----
    #pragma unroll
    for (int m = 0; m < 4; ++m) {
        const int tokb = wm * 64 + m * 16 + g * 4;
        #pragma unroll
        for (int n = 0; n < 2; ++n) {
            const int dim = wn * 32 + n * 16 + r15;
            #pragma unroll
            for (int r = 0; r < 4; ++r) {
                const int tok  = tokb + r;
                const int slot = (dim >> 3) ^ (tok & 7);
                sm.u.C[tok][slot * 8 + (dim & 7)] = h2u((_Float16)acc[m][n][r]);
            }
        }
    }
    #pragma unroll
    for (int m = 0; m < 4; ++m) {
        #pragma unroll
        for (int r = 0; r < 4; ++r) {
            float s = acc[m][0][r] * acc[m][0][r] + acc[m][1][r] * acc[m][1][r];
            s += __shfl_xor(s, 1); s += __shfl_xor(s, 2);
            s += __shfl_xor(s, 4); s += __shfl_xor(s, 8);
            if (r15 == 0) sm.pnorm[wn][wm * 64 + m * 16 + g * 4 + r] = s;
        }
    }
    if (tid < BM) sm.mk[tid] = (unsigned char)(dmask[(size_t)b * LD + c * BM + tid] != 0);
    __syncthreads();

    // ---- epilogue 2: sim GEMM [32 q] x [16 tokens per wave], K=128 ----
    const unsigned short* qb = qn + (size_t)(b / ppq) * LQ * DIM;
    const int tok = w * 16 + r15;
    const float inv = 1.0f / fmaxf(sqrtf(sm.pnorm[0][tok] + sm.pnorm[1][tok] +
                                         sm.pnorm[2][tok] + sm.pnorm[3][tok]), EPSF);
    const int msk = sm.mk[tok];

    f32x4 sacc[2];
    sacc[0] = (f32x4){0.f, 0.f, 0.f, 0.f};
    sacc[1] = (f32x4){0.f, 0.f, 0.f, 0.f};
    #pragma unroll
    for (int ks = 0; ks < 4; ++ks) {
        const int slot = (ks * 4 + g) ^ (tok & 7);
        f16x8 cb = *(const f16x8*)&sm.u.C[tok][slot * 8];
        #pragma unroll
        for (int m = 0; m < 2; ++m) {
            f16x8 qa = *(const f16x8*)(qb + (size_t)(m * 16 + r15) * DIM + ks * 32 + g * 8);
            sacc[m] = __builtin_amdgcn_mfma_f32_16x16x32_f16(qa, cb, sacc[m], 0, 0, 0);
        }
    }

    #pragma unroll
    for (int m = 0; m < 2; ++m) {
        #pragma unroll
        for (int r = 0; r < 4; ++r) {
            float v = msk ? sacc[m][r] * inv : -INFINITY;
            v = fmaxf(v, __shfl_xor(v, 1));
            v = fmaxf(v, __shfl_xor(v, 2));
            v = fmaxf(v, __shfl_xor(v, 4));
            v = fmaxf(v, __shfl_xor(v, 8));
            if (r15 == 0) sm.pmax[m * 16 + g * 4 + r][w] = v;
        }
    }
    __syncthreads();
    if (tid < LQ) {
        float mv = sm.pmax[tid][0];
        #pragma unroll
        for (int j = 1; j < 8; ++j) mv = fmaxf(mv, sm.pmax[tid][j]);
        part[(size_t)blk * 32 + tid] = mv;
    }
}

// ---------------- final: max over 4 chunks, sum over queries ----------------
__global__ __launch_bounds__(64) void final_kernel(
    const float* __restrict__ part, float* __restrict__ out)
{
    const int b = blockIdx.x;
    const int q = threadIdx.x & 31;
    const float* p = part + (size_t)b * 128;
    float m = fmaxf(fmaxf(p[q], p[32 + q]), fmaxf(p[64 + q], p[96 + q]));
    #pragma unroll
    for (int off = 1; off < 32; off <<= 1) m += __shfl_xor(m, off);
    if (threadIdx.x == 0) out[b] = m;
}

extern "C" void kernel_launch(void* const* d_in, const int* in_sizes, int n_in,
                              void* d_out, int out_size, void* d_ws, size_t ws_size,
                              hipStream_t stream) {
    const float* qh    = (const float*)d_in[0];
    const float* dh    = (const float*)d_in[1];
    const float* W     = (const float*)d_in[2];
    const int*   dmask = (const int*)d_in[3];
    const int*   ppq   = (const int*)d_in[4];
    float*       out   = (float*)d_out;

    unsigned short* wsW  = (unsigned short*)d_ws;                      // 192 KB
    float*          WT   = (float*)((char*)d_ws + 196608);             // 384 KB
    unsigned short* qn   = (unsigned short*)((char*)d_ws + 589824);    // 256 KB
    float*          part = (float*)((char*)d_ws + 851968);             // 128 KB

    const int nq = in_sizes[0] / H;      // 1024 query tokens
    const int Bd = out_size;             // 256 docs

    wconv_kernel<<<NT, 256, 0, stream>>>(W, wsW, WT);
    qproj_kernel<<<nq / 4, 256, 0, stream>>>(qh, WT, qn);
    docgemm_kernel<<<Bd * 4, 512, 0, stream>>>(dh, wsW, dmask, qn, part, ppq);
    final_kernel<<<Bd, 64, 0, stream>>>(part, out);
}